// Round 3
// baseline (357.224 us; speedup 1.0000x reference)
//
#include <hip/hip_runtime.h>

// TensorProduct: 128x0e+128x1o (x1) ⊗ 1x0e+1x1o (x2) -> 128x0e+128x1o, 'uvw' weights.
//
// Folded single-GEMM formulation (scalars b into A-rows, norms into weights):
//   out0[z,w]   = [b0*a0 ; a1·b1]   @ V0,  V0 = [W0/16 ; W3/(16*sqrt3)]  (256x128)
//   out1[z,w,k] = [b1k*a0 ; b0*a1k] @ V1,  V1 = [W1/16 ; W2/16]          (256x128)
// Memory floor ~49-65us (write 205MB must hit HBM; fetch ~104MB after L3).
//
// History:
//  r0: no pipeline, 2 blk/CU, __syncthreads: 143us @36% BW. latency-serialized.
//  r1: +reg prefetch under bounds(512,4): 128-reg budget -> TileRegs spilled
//      to scratch (FETCH+WRITE +500GB, 283us). Tell: VGPR_Count stuck at 64.
//  r2: bounds(512,2) (256-reg budget, no spill, VGPR 120+64agpr) + packed F3
//      out1 stores (WRITE 249->200GB = ideal): 125us @31% BW. Still stalled:
//      __syncthreads emits s_waitcnt vmcnt(0) before s_barrier -> every tile
//      waits for its 16 output stores AND the 9 prefetch loads at the barrier.
//      The prefetch overlap was structurally cancelled by barrier semantics.
//  r3 (this): T4 counted-wait barriers (m201 pattern). Replace __syncthreads
//      with {s_waitcnt lgkmcnt(0); s_barrier} + sched_barrier(0) fences.
//      Neither barrier needs vmcnt: bar1 = ds_writes visible (lgkmcnt), bar2 =
//      own ds_reads landed in regs (lgkmcnt). Load->use and store->acc-reuse
//      hazards are left to the compiler's per-register scoreboard (minimal
//      counted waits): stores drain under the next stage phase, prefetch loads
//      complete under the MFMA phase. Memory pipe streams continuously.
//
// C/D layout (m89-verified): col = lane&15 (=n), row = (lane>>4)*4 + reg (=m).

#define Z_TOTAL   100000
#define BM        32
#define NTILES_Z  (Z_TOTAL / BM)   // 3125, exact
#define GRID      256
#define THREADS   512

using bf16x8 = __attribute__((ext_vector_type(8))) __bf16;
using f32x4  = __attribute__((ext_vector_type(4))) float;

struct __align__(4) F3 { float x, y, z; };   // 12B packed out1 store

struct TileRegs {
    float4 b;          // x2 row: b0, b1x, b1y, b1z
    float4 a0a, a0b;   // 8 floats of a0 chunk
    float4 a1[6];      // 24 floats of a1 chunk (u,3 interleaved)
};

// Raw barrier with LDS-only drain: no vmcnt(0), so global loads/stores stay
// in flight across it. sched_barrier(0) pins ds ops on the correct side
// (rule #18: compiler may hoist reg-only ops past bare asm waitcnt).
__device__ __forceinline__ void bar_lds() {
    __builtin_amdgcn_sched_barrier(0);
    asm volatile("s_waitcnt lgkmcnt(0)");
    __builtin_amdgcn_s_barrier();
    __builtin_amdgcn_sched_barrier(0);
}

// LDS: 128 rows x 256 bf16 (512B rows). chunk = 16B unit index (0..31).
// XOR-swizzle low 3 bits of chunk by (row&7): conflict-floor for writes+reads.
__device__ __forceinline__ int lds_idx(int row, int chunk) {
    return row * 256 + ((chunk ^ (row & 7)) << 3);
}

__device__ __forceinline__ void tile_load(TileRegs& T, const float* __restrict__ x1,
                                          const float* __restrict__ x2,
                                          int z0, int zl, int u0) {
    const float* xr = x1 + (size_t)(z0 + zl) * 512;
    T.b   = *(const float4*)(x2 + (size_t)(z0 + zl) * 4);
    T.a0a = *(const float4*)(xr + u0);
    T.a0b = *(const float4*)(xr + u0 + 4);
    #pragma unroll
    for (int i = 0; i < 6; ++i)
        T.a1[i] = *(const float4*)(xr + 128 + u0 * 3 + i * 4);
}

__device__ __forceinline__ void tile_stage(const TileRegs& T, unsigned short* lds,
                                           int zl, int ug) {
    const float b0 = T.b.x, b1x = T.b.y, b1y = T.b.z, b1z = T.b.w;
    const float a0[8] = {T.a0a.x, T.a0a.y, T.a0a.z, T.a0a.w,
                         T.a0b.x, T.a0b.y, T.a0b.z, T.a0b.w};
    bf16x8 pk;
    #pragma unroll
    for (int i = 0; i < 8; ++i) pk[i] = (__bf16)(b0 * a0[i]);
    *(bf16x8*)&lds[lds_idx(zl, ug)] = pk;              // R0 lo: b0*a0
    #pragma unroll
    for (int i = 0; i < 8; ++i) pk[i] = (__bf16)(b1x * a0[i]);
    *(bf16x8*)&lds[lds_idx(32 + zl, ug)] = pk;         // R1x lo
    #pragma unroll
    for (int i = 0; i < 8; ++i) pk[i] = (__bf16)(b1y * a0[i]);
    *(bf16x8*)&lds[lds_idx(64 + zl, ug)] = pk;         // R1y lo
    #pragma unroll
    for (int i = 0; i < 8; ++i) pk[i] = (__bf16)(b1z * a0[i]);
    *(bf16x8*)&lds[lds_idx(96 + zl, ug)] = pk;         // R1z lo

    float a1[24];
    #pragma unroll
    for (int i = 0; i < 6; ++i) {
        a1[i*4+0] = T.a1[i].x; a1[i*4+1] = T.a1[i].y;
        a1[i*4+2] = T.a1[i].z; a1[i*4+3] = T.a1[i].w;
    }
    #pragma unroll
    for (int i = 0; i < 8; ++i)                        // R0 hi: a1·b1 (1/sqrt3 in V0)
        pk[i] = (__bf16)(a1[3*i]*b1x + a1[3*i+1]*b1y + a1[3*i+2]*b1z);
    *(bf16x8*)&lds[lds_idx(zl, 16 + ug)] = pk;
    #pragma unroll
    for (int i = 0; i < 8; ++i) pk[i] = (__bf16)(b0 * a1[3*i + 0]);
    *(bf16x8*)&lds[lds_idx(32 + zl, 16 + ug)] = pk;    // R1x hi: b0*a1x
    #pragma unroll
    for (int i = 0; i < 8; ++i) pk[i] = (__bf16)(b0 * a1[3*i + 1]);
    *(bf16x8*)&lds[lds_idx(64 + zl, 16 + ug)] = pk;    // R1y hi
    #pragma unroll
    for (int i = 0; i < 8; ++i) pk[i] = (__bf16)(b0 * a1[3*i + 2]);
    *(bf16x8*)&lds[lds_idx(96 + zl, 16 + ug)] = pk;    // R1z hi
}

__device__ __forceinline__ void mfma_store(const unsigned short* lds,
                                           const bf16x8 Bf[2][8],
                                           float* __restrict__ out,
                                           int z0, int m16, int q, int n) {
    // out0: rows 0..31 of A, weights V0. 16 consecutive lanes write 64B
    // line-aligned -> full-line writes already.
    #pragma unroll
    for (int m2 = 0; m2 < 2; ++m2) {
        f32x4 acc = {0.f, 0.f, 0.f, 0.f};
        const int r = m2 * 16 + m16;
        #pragma unroll
        for (int kt = 0; kt < 8; ++kt) {
            const bf16x8 a = *(const bf16x8*)&lds[lds_idx(r, kt * 4 + q)];
            acc = __builtin_amdgcn_mfma_f32_16x16x32_bf16(a, Bf[0][kt], acc, 0, 0, 0);
        }
        #pragma unroll
        for (int reg = 0; reg < 4; ++reg) {
            const int z = z0 + m2 * 16 + q * 4 + reg;
            out[(size_t)z * 512 + n] = acc[reg];
        }
    }
    // out1: zt-major so the k3 triplet is live together -> packed 12B stores
    // (lane m16 writes bytes [12*m16, 12*m16+12) of the wave's 192B span:
    //  byte-contiguous, 64B-line-aligned per wave -> no partial-line RMW).
    #pragma unroll
    for (int zt = 0; zt < 2; ++zt) {
        f32x4 a3[3];
        #pragma unroll
        for (int k3 = 0; k3 < 3; ++k3) {
            a3[k3] = (f32x4){0.f, 0.f, 0.f, 0.f};
            const int r = 32 + k3 * 32 + zt * 16 + m16;
            #pragma unroll
            for (int kt = 0; kt < 8; ++kt) {
                const bf16x8 a = *(const bf16x8*)&lds[lds_idx(r, kt * 4 + q)];
                a3[k3] = __builtin_amdgcn_mfma_f32_16x16x32_bf16(a, Bf[1][kt], a3[k3], 0, 0, 0);
            }
        }
        #pragma unroll
        for (int reg = 0; reg < 4; ++reg) {
            const int z = z0 + zt * 16 + q * 4 + reg;
            F3 v; v.x = a3[0][reg]; v.y = a3[1][reg]; v.z = a3[2][reg];
            *(F3*)(out + (size_t)z * 512 + 128 + n * 3) = v;
        }
    }
}

__global__ __launch_bounds__(THREADS, 2)   // 2 waves/SIMD -> 256 regs/wave: P/N+Bf fit
void tp_kernel(const float* __restrict__ x1, const float* __restrict__ x2,
               const float* __restrict__ wts, float* __restrict__ out)
{
    __shared__ __align__(16) unsigned short lds[128 * 256];   // 64 KB

    const int t    = threadIdx.x;
    const int lane = t & 63;
    const int wv   = t >> 6;        // wave id 0..7 == n-tile
    const int m16  = lane & 15;
    const int q    = lane >> 4;

    // ---- persistent B fragments (weights), 64 regs/lane ----
    const float S16 = 0.0625f;                                // 1/16
    const float S48 = 0.0625f * 0.57735026918962576f;         // 1/(16*sqrt(3))
    bf16x8 Bf[2][8];
    {
        const int n = wv * 16 + m16;
        #pragma unroll
        for (int mat = 0; mat < 2; ++mat) {
            #pragma unroll
            for (int kt = 0; kt < 8; ++kt) {
                bf16x8 bb;
                #pragma unroll
                for (int j = 0; j < 8; ++j) {
                    const int k = kt * 32 + q * 8 + j;
                    float v;
                    if (mat == 0) {  // V0 = [W0/16 ; W3/(16*sqrt3)]
                        v = (k < 128) ? wts[k * 128 + n] * S16
                                      : wts[49152 + (k - 128) * 128 + n] * S48;
                    } else {         // V1 = [W1/16 ; W2/16]
                        v = (k < 128) ? wts[16384 + k * 128 + n] * S16
                                      : wts[32768 + (k - 128) * 128 + n] * S16;
                    }
                    bb[j] = (__bf16)v;
                }
                Bf[mat][kt] = bb;
            }
        }
    }

    const int zl = t >> 4;          // local z row 0..31
    const int ug = t & 15;          // u-group (8 u's per thread)
    const int u0 = ug * 8;
    const int n  = wv * 16 + m16;

    // ---- software pipeline: 2x-unrolled, alternating P/N register tiles ----
    int tile = blockIdx.x;          // GRID=256 < NTILES_Z: every block has >=1 tile
    TileRegs P, N;
    tile_load(P, x1, x2, tile * BM, zl, u0);

    for (;;) {
        int nx = tile + GRID;
        bar_lds();                       // LDS reuse guard (prev reads in regs)
        tile_stage(P, lds, zl, ug);      // compiler waits P's loads (vmcnt, counted)
        bar_lds();                       // ds_writes visible to all waves
        if (nx < NTILES_Z)               // prefetch stays in flight across barriers
            tile_load(N, x1, x2, nx * BM, zl, u0);
        mfma_store(lds, Bf, out, tile * BM, m16, q, n);
        if (nx >= NTILES_Z) return;      // trailing stores drain at kernel end
        tile = nx;

        nx = tile + GRID;
        bar_lds();
        tile_stage(N, lds, zl, ug);
        bar_lds();
        if (nx < NTILES_Z)
            tile_load(P, x1, x2, nx * BM, zl, u0);
        mfma_store(lds, Bf, out, tile * BM, m16, q, n);
        if (nx >= NTILES_Z) return;
        tile = nx;
    }
}

extern "C" void kernel_launch(void* const* d_in, const int* in_sizes, int n_in,
                              void* d_out, int out_size, void* d_ws, size_t ws_size,
                              hipStream_t stream) {
    (void)in_sizes; (void)n_in; (void)d_ws; (void)ws_size; (void)out_size;
    const float* x1  = (const float*)d_in[0];
    const float* x2  = (const float*)d_in[1];
    const float* wts = (const float*)d_in[2];
    float* out = (float*)d_out;
    tp_kernel<<<dim3(GRID), dim3(THREADS), 0, stream>>>(x1, x2, wts, out);
}

// Round 4
// 355.545 us; speedup vs baseline: 1.0047x; 1.0047x over previous
//
#include <hip/hip_runtime.h>

// TensorProduct: 128x0e+128x1o (x1) ⊗ 1x0e+1x1o (x2) -> 128x0e+128x1o, 'uvw' weights.
//
// Folded single-GEMM formulation (scalars b into A-rows, norms into weights):
//   out0[z,w]   = [b0*a0 ; a1·b1]   @ V0,  V0 = [W0/16 ; W3/(16*sqrt3)]  (256x128)
//   out1[z,w,k] = [b1k*a0 ; b0*a1k] @ V1,  V1 = [W1/16 ; W2/16]          (256x128)
// Memory floor ~49-65us (write 205MB must hit HBM; fetch ~104MB after L3).
//
// History:
//  r0: 2 blk/CU, no pipeline, __syncthreads, dword out1 scatter: 143us @36%.
//  r1: +reg prefetch @bounds(512,4): 128-reg budget -> TileRegs spilled to
//      scratch (FETCH+WRITE +500GB, 283us). Tell: VGPR_Count stuck at 64.
//  r2: bounds(512,2)+GRID=256 (no spill) + packed F3 out1 stores (WRITE
//      249->200GB = ideal): 125us @31% BW.
//  r3: counted-wait barriers (no vmcnt drain): NULL (123us). Barrier drain was
//      NOT the constraint. Budget: tile should be max(mem 5.2us, CU ~3us) but
//      measures 10us -> memory duty cycle ~40%: ONE block/CU, 8 waves in
//      lockstep, loads burst once per tile then the pipe idles through the
//      stage/LDS/MFMA phases; every exposed wait stalls the whole CU.
//  r4 (this): TLP instead of reg-pipeline. 2 blocks/CU (GRID=512,
//      bounds(512,4); prefetch removed so 128-reg budget holds, r0-proven).
//      Two blocks at independent barrier phases cover each other's load
//      latency and keep memory streaming (m114 wave-overlap). Keep packed F3
//      stores + counted bar_lds barriers. Loads issue as one early batch
//      pinned by sched_barrier(0) before converts.
//
// C/D layout (m89-verified): col = lane&15 (=n), row = (lane>>4)*4 + reg (=m).

#define Z_TOTAL   100000
#define BM        32
#define NTILES_Z  (Z_TOTAL / BM)   // 3125, exact
#define GRID      512
#define THREADS   512

using bf16x8 = __attribute__((ext_vector_type(8))) __bf16;
using f32x4  = __attribute__((ext_vector_type(4))) float;

struct __align__(4) F3 { float x, y, z; };   // 12B packed out1 store

// Raw barrier with LDS-only drain: no vmcnt(0), so global loads/stores stay
// in flight across it. sched_barrier(0) pins ds ops on the correct side
// (rule #18: compiler may hoist reg-only ops past bare asm waitcnt).
__device__ __forceinline__ void bar_lds() {
    __builtin_amdgcn_sched_barrier(0);
    asm volatile("s_waitcnt lgkmcnt(0)");
    __builtin_amdgcn_s_barrier();
    __builtin_amdgcn_sched_barrier(0);
}

// LDS: 128 rows x 256 bf16 (512B rows). chunk = 16B unit index (0..31).
// XOR-swizzle low 3 bits of chunk by (row&7): conflict-floor for writes+reads.
__device__ __forceinline__ int lds_idx(int row, int chunk) {
    return row * 256 + ((chunk ^ (row & 7)) << 3);
}

__device__ __forceinline__ void tile_stage(const float* __restrict__ xr,
                                           const float* __restrict__ x2r,
                                           unsigned short* lds, int zl, int ug) {
    const int u0 = ug * 8;
    // ---- issue all 9 global loads first (one burst per tile) ----
    const float4 b4  = *(const float4*)x2r;
    const float4 a0a = *(const float4*)(xr + u0);
    const float4 a0b = *(const float4*)(xr + u0 + 4);
    float4 a1v[6];
    #pragma unroll
    for (int i = 0; i < 6; ++i)
        a1v[i] = *(const float4*)(xr + 128 + u0 * 3 + i * 4);
    __builtin_amdgcn_sched_barrier(0);   // don't sink loads below the converts

    const float b0 = b4.x, b1x = b4.y, b1y = b4.z, b1z = b4.w;
    const float a0[8] = {a0a.x, a0a.y, a0a.z, a0a.w, a0b.x, a0b.y, a0b.z, a0b.w};
    bf16x8 pk;
    #pragma unroll
    for (int i = 0; i < 8; ++i) pk[i] = (__bf16)(b0 * a0[i]);
    *(bf16x8*)&lds[lds_idx(zl, ug)] = pk;              // R0 lo: b0*a0
    #pragma unroll
    for (int i = 0; i < 8; ++i) pk[i] = (__bf16)(b1x * a0[i]);
    *(bf16x8*)&lds[lds_idx(32 + zl, ug)] = pk;         // R1x lo
    #pragma unroll
    for (int i = 0; i < 8; ++i) pk[i] = (__bf16)(b1y * a0[i]);
    *(bf16x8*)&lds[lds_idx(64 + zl, ug)] = pk;         // R1y lo
    #pragma unroll
    for (int i = 0; i < 8; ++i) pk[i] = (__bf16)(b1z * a0[i]);
    *(bf16x8*)&lds[lds_idx(96 + zl, ug)] = pk;         // R1z lo

    float a1[24];
    #pragma unroll
    for (int i = 0; i < 6; ++i) {
        a1[i*4+0] = a1v[i].x; a1[i*4+1] = a1v[i].y;
        a1[i*4+2] = a1v[i].z; a1[i*4+3] = a1v[i].w;
    }
    #pragma unroll
    for (int i = 0; i < 8; ++i)                        // R0 hi: a1·b1 (1/sqrt3 in V0)
        pk[i] = (__bf16)(a1[3*i]*b1x + a1[3*i+1]*b1y + a1[3*i+2]*b1z);
    *(bf16x8*)&lds[lds_idx(zl, 16 + ug)] = pk;
    #pragma unroll
    for (int i = 0; i < 8; ++i) pk[i] = (__bf16)(b0 * a1[3*i + 0]);
    *(bf16x8*)&lds[lds_idx(32 + zl, 16 + ug)] = pk;    // R1x hi: b0*a1x
    #pragma unroll
    for (int i = 0; i < 8; ++i) pk[i] = (__bf16)(b0 * a1[3*i + 1]);
    *(bf16x8*)&lds[lds_idx(64 + zl, 16 + ug)] = pk;    // R1y hi
    #pragma unroll
    for (int i = 0; i < 8; ++i) pk[i] = (__bf16)(b0 * a1[3*i + 2]);
    *(bf16x8*)&lds[lds_idx(96 + zl, 16 + ug)] = pk;    // R1z hi
}

__device__ __forceinline__ void mfma_store(const unsigned short* lds,
                                           const bf16x8 Bf[2][8],
                                           float* __restrict__ out,
                                           int z0, int m16, int q, int n) {
    // out0: rows 0..31 of A, weights V0. 16 consecutive lanes write 64B
    // line-aligned -> full-line writes already.
    #pragma unroll
    for (int m2 = 0; m2 < 2; ++m2) {
        f32x4 acc = {0.f, 0.f, 0.f, 0.f};
        const int r = m2 * 16 + m16;
        #pragma unroll
        for (int kt = 0; kt < 8; ++kt) {
            const bf16x8 a = *(const bf16x8*)&lds[lds_idx(r, kt * 4 + q)];
            acc = __builtin_amdgcn_mfma_f32_16x16x32_bf16(a, Bf[0][kt], acc, 0, 0, 0);
        }
        #pragma unroll
        for (int reg = 0; reg < 4; ++reg) {
            const int z = z0 + m2 * 16 + q * 4 + reg;
            out[(size_t)z * 512 + n] = acc[reg];
        }
    }
    // out1: zt-major so the k3 triplet is live together -> packed 12B stores
    // (lane m16 writes bytes [12*m16, 12*m16+12) of the wave's 192B span:
    //  byte-contiguous, 64B-line-aligned per wave -> no partial-line RMW).
    #pragma unroll
    for (int zt = 0; zt < 2; ++zt) {
        f32x4 a3[3];
        #pragma unroll
        for (int k3 = 0; k3 < 3; ++k3) {
            a3[k3] = (f32x4){0.f, 0.f, 0.f, 0.f};
            const int r = 32 + k3 * 32 + zt * 16 + m16;
            #pragma unroll
            for (int kt = 0; kt < 8; ++kt) {
                const bf16x8 a = *(const bf16x8*)&lds[lds_idx(r, kt * 4 + q)];
                a3[k3] = __builtin_amdgcn_mfma_f32_16x16x32_bf16(a, Bf[1][kt], a3[k3], 0, 0, 0);
            }
        }
        #pragma unroll
        for (int reg = 0; reg < 4; ++reg) {
            const int z = z0 + zt * 16 + q * 4 + reg;
            F3 v; v.x = a3[0][reg]; v.y = a3[1][reg]; v.z = a3[2][reg];
            *(F3*)(out + (size_t)z * 512 + 128 + n * 3) = v;
        }
    }
}

__global__ __launch_bounds__(THREADS, 4)   // 128 regs/wave -> 2 blocks/CU (r0-proven fit)
void tp_kernel(const float* __restrict__ x1, const float* __restrict__ x2,
               const float* __restrict__ wts, float* __restrict__ out)
{
    __shared__ __align__(16) unsigned short lds[128 * 256];   // 64 KB (2 blocks = 128KB/CU)

    const int t    = threadIdx.x;
    const int lane = t & 63;
    const int wv   = t >> 6;        // wave id 0..7 == n-tile
    const int m16  = lane & 15;
    const int q    = lane >> 4;

    // ---- persistent B fragments (weights), 64 regs/lane (AGPR-resident) ----
    const float S16 = 0.0625f;                                // 1/16
    const float S48 = 0.0625f * 0.57735026918962576f;         // 1/(16*sqrt(3))
    bf16x8 Bf[2][8];
    {
        const int n = wv * 16 + m16;
        #pragma unroll
        for (int mat = 0; mat < 2; ++mat) {
            #pragma unroll
            for (int kt = 0; kt < 8; ++kt) {
                bf16x8 bb;
                #pragma unroll
                for (int j = 0; j < 8; ++j) {
                    const int k = kt * 32 + q * 8 + j;
                    float v;
                    if (mat == 0) {  // V0 = [W0/16 ; W3/(16*sqrt3)]
                        v = (k < 128) ? wts[k * 128 + n] * S16
                                      : wts[49152 + (k - 128) * 128 + n] * S48;
                    } else {         // V1 = [W1/16 ; W2/16]
                        v = (k < 128) ? wts[16384 + k * 128 + n] * S16
                                      : wts[32768 + (k - 128) * 128 + n] * S16;
                    }
                    bb[j] = (__bf16)v;
                }
                Bf[mat][kt] = bb;
            }
        }
    }

    const int zl = t >> 4;          // local z row 0..31
    const int ug = t & 15;          // u-group (8 u's per thread)
    const int n  = wv * 16 + m16;

    for (int tile = blockIdx.x; tile < NTILES_Z; tile += GRID) {
        const int z0 = tile * BM;
        bar_lds();                       // prev tile's LDS reads complete
        tile_stage(x1 + (size_t)(z0 + zl) * 512,
                   x2 + (size_t)(z0 + zl) * 4, lds, zl, ug);
        bar_lds();                       // ds_writes visible to all waves
        mfma_store(lds, Bf, out, z0, m16, q, n);
    }
}

extern "C" void kernel_launch(void* const* d_in, const int* in_sizes, int n_in,
                              void* d_out, int out_size, void* d_ws, size_t ws_size,
                              hipStream_t stream) {
    (void)in_sizes; (void)n_in; (void)d_ws; (void)ws_size; (void)out_size;
    const float* x1  = (const float*)d_in[0];
    const float* x2  = (const float*)d_in[1];
    const float* wts = (const float*)d_in[2];
    float* out = (float*)d_out;
    tp_kernel<<<dim3(GRID), dim3(THREADS), 0, stream>>>(x1, x2, wts, out);
}